// Round 10
// baseline (511.507 us; speedup 1.0000x reference)
//
#include <hip/hip_runtime.h>
#include <hip/hip_bf16.h>
#include <math.h>

#define L_SEQ 8192
#define NFFT  16384
#define NPAD  16896   // NFFT + NFFT/32 padding (floats per array)
#define F_DIM 768
#define D_DIM 768
#define C_IN  2304    // INNER = F*(ORDER+1)
#define NORD  2
#define NT    512
#define TWO_PI 6.2831853071795864769f

typedef unsigned short u16;
typedef __attribute__((ext_vector_type(8))) short bf16x8;
typedef __attribute__((ext_vector_type(4))) float f32x4;
struct __align__(8) U16x4 { u16 x, y, z, w; };

__device__ __forceinline__ float bf2f(u16 v) {
  unsigned u = ((unsigned)v) << 16; float f; __builtin_memcpy(&f, &u, 4); return f;
}
__device__ __forceinline__ u16 f2bf(float f) {
  __hip_bfloat16 h = __float2bfloat16(f); u16 r; __builtin_memcpy(&r, &h, 2); return r;
}

// LDS pad: bank(i) shifts by 1 every 32 floats -> all FFT strides <=2-way (free).
// NOTE: pad stride 1 breaks 8/16B alignment classes -> LDS access must stay b32.
__device__ __forceinline__ int PAD(int i) { return i + (i >> 5); }

// reverse the 7 base-4 digits of a 14-bit index (DIF output permutation: k = rev4(p))
__device__ __forceinline__ int rev4_14(int p) {
  return ((p & 0x0003) << 12) | ((p & 0x000C) << 8) | ((p & 0x0030) << 4)
       | ( p & 0x00C0       ) | ((p & 0x0300) >> 4) | ((p & 0x0C00) >> 8)
       | ((p & 0x3000) >> 12);
}

__device__ __forceinline__ void rot3(float ang, float& c1, float& s1,
                                     float& c2, float& s2, float& c3, float& s3)
{
  __sincosf(ang, &s1, &c1);
  c2 = c1 * c1 - s1 * s1; s2 = 2.0f * c1 * s1;
  c3 = c1 * c2 - s1 * s2; s3 = c1 * s2 + s1 * c2;
}

// depthwise conv3 on a bf16 row, SAME padding (XLA cross-correlation)
__device__ __forceinline__ float conv3b(const u16* __restrict__ row, int t,
                                        float w0, float w1, float w2, float sb)
{
  float l = (t > 0)         ? bf2f(row[t - 1]) : 0.0f;
  float c = bf2f(row[t]);
  float r = (t < L_SEQ - 1) ? bf2f(row[t + 1]) : 0.0f;
  return w0 * l + w1 * c + w2 * r + sb;
}

// ===========================================================================
// Radix-4 FFT, N = 16384 = 4^7, PLANAR zr/zi in LDS (b32, 2-way-free PAD).
// Stage algebra verbatim from the verified round-0/round-7 kernels.
// ===========================================================================

// layer-2 (stage 10) + planar stores of the first fwd pair. g in [0,1024).
__device__ __forceinline__ void s1_l2_store(float* zr, float* zi, int g,
    const float yr[4][4], const float yi4[4][4])
{
  const float stw2 = -TWO_PI / 4096.0f;
  float c1, s1, c2, s2, c3, s3;
  rot3(stw2 * (float)g, c1, s1, c2, s2, c3, s3);
  #pragma unroll
  for (int k = 0; k < 4; ++k) {
    float t0r = yr[k][0] + yr[k][2], t0i = yi4[k][0] + yi4[k][2];
    float t1r = yr[k][0] - yr[k][2], t1i = yi4[k][0] - yi4[k][2];
    float t2r = yr[k][1] + yr[k][3], t2i = yi4[k][1] + yi4[k][3];
    float t3r = yr[k][1] - yr[k][3], t3i = yi4[k][1] - yi4[k][3];
    float o0r = t0r + t2r, o0i = t0i + t2i;
    float o1r = t1r + t3i, o1i = t1i - t3r;
    float o2r = t0r - t2r, o2i = t0i - t2i;
    float o3r = t1r - t3i, o3i = t1i + t3r;
    const int i0 = g + (k << 12);
    zr[PAD(i0       )] = o0r;               zi[PAD(i0       )] = o0i;
    zr[PAD(i0 + 1024)] = o1r*c1 - o1i*s1;   zi[PAD(i0 + 1024)] = o1r*s1 + o1i*c1;
    zr[PAD(i0 + 2048)] = o2r*c2 - o2i*s2;   zi[PAD(i0 + 2048)] = o2r*s2 + o2i*c2;
    zr[PAD(i0 + 3072)] = o3r*c3 - o3i*s3;   zi[PAD(i0 + 3072)] = o3r*s3 + o3i*c3;
  }
}

// stage-1 layer-1 with k=2,3 inputs == 0 (zero-padded upper half).
__device__ __forceinline__ void s1_zero_hi(float* zr, float* zi, int g,
    const float xr[2][4], const float xi[2][4])
{
  const float stw1 = -TWO_PI / 16384.0f;
  float yr[4][4], yi4[4][4];
  #pragma unroll
  for (int m = 0; m < 4; ++m) {
    const float x0r = xr[0][m], x0i = xi[0][m];
    const float x1r = xr[1][m], x1i = xi[1][m];
    const float y0r = x0r + x1r, y0i = x0i + x1i;
    const float y1r = x0r + x1i, y1i = x0i - x1r;
    const float y2r = x0r - x1r, y2i = x0i - x1i;
    const float y3r = x0r - x1i, y3i = x0i + x1r;
    float c1, s1, c2, s2, c3, s3;
    rot3(stw1 * (float)(g + (m << 10)), c1, s1, c2, s2, c3, s3);
    yr[0][m] = y0r;               yi4[0][m] = y0i;
    yr[1][m] = y1r*c1 - y1i*s1;   yi4[1][m] = y1r*s1 + y1i*c1;
    yr[2][m] = y2r*c2 - y2i*s2;   yi4[2][m] = y2r*s2 + y2i*c2;
    yr[3][m] = y3r*c3 - y3i*s3;   yi4[3][m] = y3r*s3 + y3i*c3;
  }
  s1_l2_store(zr, zi, g, yr, yi4);
}

// fwd pairs (lq, lq-2) down to (4,2) — generic planar body verbatim from round 0.
// LQ0 = 8 (after a fused stage-1 pair) or 12 (full FFT from LDS input).
template<int LQ0>
__device__ __forceinline__ void fwd_pairs(float* zr, float* zi, int tid)
{
  #pragma unroll
  for (int lq = LQ0; lq >= 4; lq -= 4) {
    const int q  = 1 << lq;
    const int q4 = q >> 2;
    const float stw1 = -TWO_PI / (float)(q << 2);
    const float stw2 = -TWO_PI / (float)q;
    for (int g = tid; g < NFFT / 16; g += NT) {
      const int j    = g & (q4 - 1);
      const int base = ((g >> (lq - 2)) << (lq + 2)) + j;
      float xr[4][4], xi4[4][4];
      #pragma unroll
      for (int k = 0; k < 4; ++k)
        #pragma unroll
        for (int m = 0; m < 4; ++m) {
          const int idx = PAD(base + m * q4 + k * q);
          xr[k][m] = zr[idx]; xi4[k][m] = zi[idx];
        }
      #pragma unroll
      for (int m = 0; m < 4; ++m) {
        float t0r = xr[0][m] + xr[2][m], t0i = xi4[0][m] + xi4[2][m];
        float t1r = xr[0][m] - xr[2][m], t1i = xi4[0][m] - xi4[2][m];
        float t2r = xr[1][m] + xr[3][m], t2i = xi4[1][m] + xi4[3][m];
        float t3r = xr[1][m] - xr[3][m], t3i = xi4[1][m] - xi4[3][m];
        float y0r = t0r + t2r, y0i = t0i + t2i;
        float y1r = t1r + t3i, y1i = t1i - t3r;
        float y2r = t0r - t2r, y2i = t0i - t2i;
        float y3r = t1r - t3i, y3i = t1i + t3r;
        float c1, s1, c2, s2, c3, s3;
        rot3(stw1 * (float)(j + m * q4), c1, s1, c2, s2, c3, s3);
        xr[0][m] = y0r;                xi4[0][m] = y0i;
        xr[1][m] = y1r * c1 - y1i * s1; xi4[1][m] = y1r * s1 + y1i * c1;
        xr[2][m] = y2r * c2 - y2i * s2; xi4[2][m] = y2r * s2 + y2i * c2;
        xr[3][m] = y3r * c3 - y3i * s3; xi4[3][m] = y3r * s3 + y3i * c3;
      }
      float c1, s1, c2, s2, c3, s3;
      rot3(stw2 * (float)j, c1, s1, c2, s2, c3, s3);
      #pragma unroll
      for (int k = 0; k < 4; ++k) {
        float t0r = xr[k][0] + xr[k][2], t0i = xi4[k][0] + xi4[k][2];
        float t1r = xr[k][0] - xr[k][2], t1i = xi4[k][0] - xi4[k][2];
        float t2r = xr[k][1] + xr[k][3], t2i = xi4[k][1] + xi4[k][3];
        float t3r = xr[k][1] - xr[k][3], t3i = xi4[k][1] - xi4[k][3];
        float y0r = t0r + t2r, y0i = t0i + t2i;
        float y1r = t1r + t3i, y1i = t1i - t3r;
        float y2r = t0r - t2r, y2i = t0i - t2i;
        float y3r = t1r - t3i, y3i = t1i + t3r;
        const int i0 = base + k * q;
        zr[PAD(i0         )] = y0r;            zi[PAD(i0         )] = y0i;
        zr[PAD(i0 +     q4)] = y1r*c1 - y1i*s1; zi[PAD(i0 +     q4)] = y1r*s1 + y1i*c1;
        zr[PAD(i0 + 2 * q4)] = y2r*c2 - y2i*s2; zi[PAD(i0 + 2 * q4)] = y2r*s2 + y2i*c2;
        zr[PAD(i0 + 3 * q4)] = y3r*c3 - y3i*s3; zi[PAD(i0 + 3 * q4)] = y3r*s3 + y3i*c3;
      }
    }
    __syncthreads();
  }
}

// fwd final radix-4 + spectrum multiply + inv head fused in registers (b32 LDS).
__device__ __forceinline__ void fused_final_spec_head(float* zr, float* zi,
    const __hip_bfloat162* __restrict__ H, int tid)
{
  for (int b = tid; b < NFFT / 4; b += NT) {
    const int i0 = b << 2;
    const int p  = PAD(i0);                  // quad never crosses pad stripe
    const float a0r = zr[p],     a0i = zi[p];
    const float a1r = zr[p + 1], a1i = zi[p + 1];
    const float a2r = zr[p + 2], a2i = zi[p + 2];
    const float a3r = zr[p + 3], a3i = zi[p + 3];
    float t0r = a0r + a2r, t0i = a0i + a2i;
    float t1r = a0r - a2r, t1i = a0i - a2i;
    float t2r = a1r + a3r, t2i = a1i + a3i;
    float t3r = a1r - a3r, t3i = a1i - a3i;
    float y0r = t0r + t2r, y0i = t0i + t2i;
    float y1r = t1r + t3i, y1i = t1i - t3r;
    float y2r = t0r - t2r, y2i = t0i - t2i;
    float y3r = t1r - t3i, y3i = t1i + t3r;
    const float4 hq = *(const float4*)&H[i0];
    __hip_bfloat162 h0, h1, h2, h3;
    __builtin_memcpy(&h0, &hq.x, 4); __builtin_memcpy(&h1, &hq.y, 4);
    __builtin_memcpy(&h2, &hq.z, 4); __builtin_memcpy(&h3, &hq.w, 4);
    float hr, hi;
    hr = __bfloat162float(h0.x); hi = __bfloat162float(h0.y);
    const float u0r = y0r*hr - y0i*hi, u0i = y0r*hi + y0i*hr;
    hr = __bfloat162float(h1.x); hi = __bfloat162float(h1.y);
    const float u1r = y1r*hr - y1i*hi, u1i = y1r*hi + y1i*hr;
    hr = __bfloat162float(h2.x); hi = __bfloat162float(h2.y);
    const float u2r = y2r*hr - y2i*hi, u2i = y2r*hi + y2i*hr;
    hr = __bfloat162float(h3.x); hi = __bfloat162float(h3.y);
    const float u3r = y3r*hr - y3i*hi, u3i = y3r*hi + y3i*hr;
    const float e0r = u0r + u2r, e0i = u0i + u2i;
    const float e1r = u0r - u2r, e1i = u0i - u2i;
    const float f0r = u1r + u3r, f0i = u1i + u3i;
    const float f1r = u1r - u3r, f1i = u1i - u3i;
    zr[p]     = e0r + f0r; zi[p]     = e0i + f0i;
    zr[p + 1] = e1r - f1i; zi[p + 1] = e1i + f1r;
    zr[p + 2] = e0r - f0r; zi[p + 2] = e0i - f0i;
    zr[p + 3] = e1r + f1i; zi[p + 3] = e1i - f1r;
  }
  __syncthreads();
}

// inv middle pairs (2,4)(6,8) — planar body verbatim from round 0
__device__ __forceinline__ void inv_mid_pairs(float* zr, float* zi, int tid)
{
  #pragma unroll
  for (int lq = 2; lq <= 6; lq += 4) {
    const int q = 1 << lq;
    const int Q = q << 2;
    const float stw1 = TWO_PI / (float)(q << 2);
    const float stw2 = TWO_PI / (float)(Q << 2);
    for (int g = tid; g < NFFT / 16; g += NT) {
      const int j    = g & (q - 1);
      const int base = ((g >> lq) << (lq + 4)) + j;
      float xr[4][4], xi4[4][4];
      #pragma unroll
      for (int k = 0; k < 4; ++k)
        #pragma unroll
        for (int m = 0; m < 4; ++m) {
          const int idx = PAD(base + m * q + k * Q);
          xr[k][m] = zr[idx]; xi4[k][m] = zi[idx];
        }
      {
        float c1, s1, c2, s2, c3, s3;
        rot3(stw1 * (float)j, c1, s1, c2, s2, c3, s3);
        #pragma unroll
        for (int k = 0; k < 4; ++k) {
          float u0r = xr[k][0], u0i = xi4[k][0];
          float u1r = xr[k][1]*c1 - xi4[k][1]*s1, u1i = xr[k][1]*s1 + xi4[k][1]*c1;
          float u2r = xr[k][2]*c2 - xi4[k][2]*s2, u2i = xr[k][2]*s2 + xi4[k][2]*c2;
          float u3r = xr[k][3]*c3 - xi4[k][3]*s3, u3i = xr[k][3]*s3 + xi4[k][3]*c3;
          float e0r = u0r + u2r, e0i = u0i + u2i;
          float e1r = u0r - u2r, e1i = u0i - u2i;
          float f0r = u1r + u3r, f0i = u1i + u3i;
          float f1r = u1r - u3r, f1i = u1i - u3i;
          xr[k][0] = e0r + f0r; xi4[k][0] = e0i + f0i;
          xr[k][1] = e1r - f1i; xi4[k][1] = e1i + f1r;
          xr[k][2] = e0r - f0r; xi4[k][2] = e0i - f0i;
          xr[k][3] = e1r + f1i; xi4[k][3] = e1i - f1r;
        }
      }
      #pragma unroll
      for (int m = 0; m < 4; ++m) {
        float c1, s1, c2, s2, c3, s3;
        rot3(stw2 * (float)(j + m * q), c1, s1, c2, s2, c3, s3);
        float u0r = xr[0][m], u0i = xi4[0][m];
        float u1r = xr[1][m]*c1 - xi4[1][m]*s1, u1i = xr[1][m]*s1 + xi4[1][m]*c1;
        float u2r = xr[2][m]*c2 - xi4[2][m]*s2, u2i = xr[2][m]*s2 + xi4[2][m]*c2;
        float u3r = xr[3][m]*c3 - xi4[3][m]*s3, u3i = xr[3][m]*s3 + xi4[3][m]*c3;
        float e0r = u0r + u2r, e0i = u0i + u2i;
        float e1r = u0r - u2r, e1i = u0i - u2i;
        float f0r = u1r + u3r, f0i = u1i + u3i;
        float f1r = u1r - u3r, f1i = u1i - u3i;
        const int i0 = base + m * q;
        zr[PAD(i0        )] = e0r + f0r; zi[PAD(i0        )] = e0i + f0i;
        zr[PAD(i0 +     Q)] = e1r - f1i; zi[PAD(i0 +     Q)] = e1i + f1r;
        zr[PAD(i0 + 2 * Q)] = e0r - f0r; zi[PAD(i0 + 2 * Q)] = e0i - f0i;
        zr[PAD(i0 + 3 * Q)] = e1r + f1i; zi[PAD(i0 + 3 * Q)] = e1i - f1r;
      }
    }
    __syncthreads();
  }
}

// inv last pair (10,12) fused with gate; outputs only t<8192 (k=0,1).
template<bool TO_GLOBAL>
__device__ __forceinline__ void inv_last_gate(float* zr, float* zi,
    const u16* __restrict__ gr0, const u16* __restrict__ gr1,
    float w0, float w1, float w2, float wb, u16* __restrict__ outv, int tid)
{
  const float stw1 = TWO_PI / 4096.0f;    // 2pi/(4q), q=1024
  const float stw2 = TWO_PI / 16384.0f;   // 2pi/(4Q), Q=4096
  for (int g = tid; g < 1024; g += NT) {
    float xr[4][4], xi4[4][4];
    #pragma unroll
    for (int k = 0; k < 4; ++k)
      #pragma unroll
      for (int m = 0; m < 4; ++m) {
        const int idx = PAD(g + (m << 10) + (k << 12));
        xr[k][m] = zr[idx]; xi4[k][m] = zi[idx];
      }
    {                                      // layer 1: stage 10, j1 = g
      float c1, s1, c2, s2, c3, s3;
      rot3(stw1 * (float)g, c1, s1, c2, s2, c3, s3);
      #pragma unroll
      for (int k = 0; k < 4; ++k) {
        float u0r = xr[k][0], u0i = xi4[k][0];
        float u1r = xr[k][1]*c1 - xi4[k][1]*s1, u1i = xr[k][1]*s1 + xi4[k][1]*c1;
        float u2r = xr[k][2]*c2 - xi4[k][2]*s2, u2i = xr[k][2]*s2 + xi4[k][2]*c2;
        float u3r = xr[k][3]*c3 - xi4[k][3]*s3, u3i = xr[k][3]*s3 + xi4[k][3]*c3;
        float e0r = u0r + u2r, e0i = u0i + u2i;
        float e1r = u0r - u2r, e1i = u0i - u2i;
        float f0r = u1r + u3r, f0i = u1i + u3i;
        float f1r = u1r - u3r, f1i = u1i - u3i;
        xr[k][0] = e0r + f0r; xi4[k][0] = e0i + f0i;
        xr[k][1] = e1r - f1i; xi4[k][1] = e1i + f1r;
        xr[k][2] = e0r - f0r; xi4[k][2] = e0i - f0i;
        xr[k][3] = e1r + f1i; xi4[k][3] = e1i - f1r;
      }
    }
    #pragma unroll
    for (int m = 0; m < 4; ++m) {          // layer 2: stage 12, j2 = g + m*1024
      float c1, s1, c2, s2, c3, s3;
      rot3(stw2 * (float)(g + (m << 10)), c1, s1, c2, s2, c3, s3);
      float u0r = xr[0][m], u0i = xi4[0][m];
      float u1r = xr[1][m]*c1 - xi4[1][m]*s1, u1i = xr[1][m]*s1 + xi4[1][m]*c1;
      float u2r = xr[2][m]*c2 - xi4[2][m]*s2, u2i = xr[2][m]*s2 + xi4[2][m]*c2;
      float u3r = xr[3][m]*c3 - xi4[3][m]*s3, u3i = xr[3][m]*s3 + xi4[3][m]*c3;
      float e0r = u0r + u2r, e0i = u0i + u2i;
      float e1r = u0r - u2r, e1i = u0i - u2i;
      float f0r = u1r + u3r, f0i = u1i + u3i;
      float f1r = u1r - u3r, f1i = u1i - u3i;
      const int t0 = g + (m << 10);        // k=0 output, t0 < 4096
      const int t1 = t0 + 4096;            // k=1 output, t1 < 8192
      const float o0r = e0r + f0r, o0i = e0i + f0i;
      const float o1r = e1r - f1i, o1i = e1i + f1r;
      const float a0 = conv3b(gr0, t0, w0, w1, w2, wb);
      const float b0 = conv3b(gr1, t0, w0, w1, w2, wb);
      const float a1 = conv3b(gr0, t1, w0, w1, w2, wb);
      const float b1 = conv3b(gr1, t1, w0, w1, w2, wb);
      if (TO_GLOBAL) {
        outv[t0]         = f2bf(o0r * a0);
        outv[L_SEQ + t0] = f2bf(o0i * b0);
        outv[t1]         = f2bf(o1r * a1);
        outv[L_SEQ + t1] = f2bf(o1i * b1);
      } else {
        zr[PAD(t0)] = o0r * a0;  zi[PAD(t0)] = o0i * b0;
        zr[PAD(t1)] = o1r * a1;  zi[PAD(t1)] = o1i * b1;
      }
      // k=2,3 outputs (t >= 8192) are never needed: not written.
    }
  }
  if (!TO_GLOBAL) __syncthreads();
}

// ===========================================================================
// Prep kernels
// ===========================================================================
__global__ __launch_bounds__(256)
void cast_bf16_kernel(const float* __restrict__ in, u16* __restrict__ out, int n4)
{
  int i = blockIdx.x * 256 + threadIdx.x;
  if (i < n4) {
    float4 v = ((const float4*)in)[i];
    U16x4 w; w.x = f2bf(v.x); w.y = f2bf(v.y); w.z = f2bf(v.z); w.w = f2bf(v.w);
    ((U16x4*)out)[i] = w;
  }
}

__global__ __launch_bounds__(256)
void transpose_cast_kernel(const float* __restrict__ in, u16* __restrict__ out,
                           int K, int N)   // in [K][N] fp32 -> out [N][K] bf16
{
  __shared__ u16 tile[32][33];
  const int n0 = blockIdx.x * 32, k0 = blockIdx.y * 32;
  const int tx = threadIdx.x & 31, ty = threadIdx.x >> 5;
  #pragma unroll
  for (int i = 0; i < 32; i += 8)
    tile[ty + i][tx] = f2bf(in[(size_t)(k0 + ty + i) * N + n0 + tx]);
  __syncthreads();
  #pragma unroll
  for (int i = 0; i < 32; i += 8)
    out[(size_t)(n0 + ty + i) * K + k0 + tx] = tile[tx][ty + i];
}

// hid[16384][64] bf16: first MLP layer on the sine positional embedding.
__global__ __launch_bounds__(256)
void hid_gen_kernel(const float* __restrict__ w1, const float* __restrict__ b1,
                    u16* __restrict__ hidb)
{
  const int tid = threadIdx.x;
  const int r  = tid & 63;
  const int tb = tid >> 6;
  const float w1v0 = w1[r];
  const float b1v  = b1[r];
  float w1c[4], w1s[4];
  #pragma unroll
  for (int p = 0; p < 4; ++p) { w1c[p] = w1[(1 + p) * 64 + r]; w1s[p] = w1[(5 + p) * 64 + r]; }
  const int tau0 = blockIdx.x * 16;
  #pragma unroll
  for (int i = 0; i < 4; ++i) {
    const int tau = tau0 + tb + i * 4;
    const float off = (tau < L_SEQ) ? (float)tau : (float)(tau - NFFT);
    float acc = b1v + off * (1.0f / 8192.0f) * w1v0;
    #pragma unroll
    for (int p = 0; p < 4; ++p) {
      const double period = 4.0 + (8188.0 * p) / 3.0;
      const float freq = (float)(6.283185307179586476925287 / period);
      float sp, cp;
      sincosf(off * freq, &sp, &cp);
      acc += cp * w1c[p] + sp * w1s[p];
    }
    hidb[(size_t)tau * 64 + r] = f2bf(sinf(acc));
  }
}

// ===========================================================================
// MFMA GEMM.  WMODE 0: up_t bf16 batch layout.  WMODE 1: fp32 [M][N].
// WMODE 2: filter h path (bf16 rows strided 2*NFFT; decay epilogue).
// ATRANS 1: A is u16 [k][m] rows with row stride ASTR (u16 units); the A-tile
//           is staged transposed via registers (fuses the v transpose).
// ===========================================================================
template<int N_DIM, int K_DIM, int WMODE, int ATRANS = 0, int ASTR = 0>
__global__ __launch_bounds__(256)
void mfma_gemm_kernel(const u16* __restrict__ A, const u16* __restrict__ B,
                      const float* __restrict__ bias, void* __restrict__ Cv,
                      const float* __restrict__ dk)
{
  constexpr int BK = 64;
  __shared__ u16 As[128 * BK];
  __shared__ u16 Bs[128 * BK];
  const int tid  = threadIdx.x;
  const int lane = tid & 63;
  const int wid  = tid >> 6;
  const int m0 = blockIdx.x * 128;
  const int n0 = blockIdx.y * 128;

  const u16* aPtr[4]; const u16* bPtr[4];
  #pragma unroll
  for (int i = 0; i < 4; ++i) {
    const int g = tid + (i << 8);
    if (ATRANS == 0)
      aPtr[i] = A + (size_t)(m0 + (g >> 3)) * K_DIM + ((g & 7) << 3);
    bPtr[i] = B + (size_t)(n0 + (g >> 3)) * K_DIM + ((g & 7) << 3);
  }

  const int wm = (wid & 1) << 6;
  const int wn = (wid >> 1) << 6;
  int aoff[4], boff[4];
  #pragma unroll
  for (int f = 0; f < 4; ++f) {
    aoff[f] = (wm + f * 16 + (lane & 15)) * BK + ((lane >> 4) << 3);
    boff[f] = (wn + f * 16 + (lane & 15)) * BK + ((lane >> 4) << 3);
  }

  f32x4 acc[4][4];
  #pragma unroll
  for (int i = 0; i < 4; ++i)
    #pragma unroll
    for (int j = 0; j < 4; ++j)
      acc[i][j] = (f32x4){0.f, 0.f, 0.f, 0.f};

  for (int k0 = 0; k0 < K_DIM; k0 += BK) {
    if (ATRANS) {
      // A[m][k] = Arow[k][m]: load 16B chunks along m (lanes vary k fastest ->
      // LDS u16 writes land 2 lanes/bank = free), write transposed into As.
      #pragma unroll
      for (int i = 0; i < 4; ++i) {
        const int g    = tid + (i << 8);
        const int krow = g & 63;
        const int mc   = g >> 6;          // 0..15
        const uint4 v = *(const uint4*)&A[(size_t)(k0 + krow) * ASTR + m0 + mc * 8];
        u16 e[8]; __builtin_memcpy(e, &v, 16);
        #pragma unroll
        for (int q = 0; q < 8; ++q)
          As[(mc * 8 + q) * BK + krow] = e[q];
      }
    } else {
      #pragma unroll
      for (int i = 0; i < 4; ++i) {
        __builtin_amdgcn_global_load_lds(
            (const __attribute__((address_space(1))) void*)aPtr[i],
            (__attribute__((address_space(3))) void*)&As[(((wid << 6) + (i << 8)) << 3)],
            16, 0, 0);
        aPtr[i] += BK;
      }
    }
    #pragma unroll
    for (int i = 0; i < 4; ++i) {
      __builtin_amdgcn_global_load_lds(
          (const __attribute__((address_space(1))) void*)bPtr[i],
          (__attribute__((address_space(3))) void*)&Bs[(((wid << 6) + (i << 8)) << 3)],
          16, 0, 0);
      bPtr[i] += BK;
    }
    __syncthreads();
    #pragma unroll
    for (int kk = 0; kk < 2; ++kk) {
      bf16x8 af[4], bg[4];
      #pragma unroll
      for (int f = 0; f < 4; ++f) af[f] = *(const bf16x8*)&As[aoff[f] + kk * 32];
      #pragma unroll
      for (int f = 0; f < 4; ++f) bg[f] = *(const bf16x8*)&Bs[boff[f] + kk * 32];
      #pragma unroll
      for (int fm = 0; fm < 4; ++fm)
        #pragma unroll
        for (int fn = 0; fn < 4; ++fn)
          acc[fm][fn] = __builtin_amdgcn_mfma_f32_16x16x32_bf16(
              af[fm], bg[fn], acc[fm][fn], 0, 0, 0);
    }
    __syncthreads();
  }

  if (WMODE == 0) {
    u16* C = (u16*)Cv;
    const int b = m0 >> 13;
    const int tbase = (m0 & (L_SEQ - 1)) + wm + ((lane >> 4) << 2);
    #pragma unroll
    for (int fn = 0; fn < 4; ++fn) {
      const int n = n0 + wn + fn * 16 + (lane & 15);
      const float bv = bias[n];
      u16* row = C + ((size_t)b * N_DIM + n) * L_SEQ;
      #pragma unroll
      for (int fm = 0; fm < 4; ++fm) {
        f32x4 v = acc[fm][fn];
        U16x4 w;
        w.x = f2bf(v[0] + bv); w.y = f2bf(v[1] + bv);
        w.z = f2bf(v[2] + bv); w.w = f2bf(v[3] + bv);
        *(U16x4*)&row[tbase + fm * 16] = w;
      }
    }
  } else if (WMODE == 1) {
    float* C = (float*)Cv;
    #pragma unroll
    for (int fn = 0; fn < 4; ++fn) {
      const int n = n0 + wn + fn * 16 + (lane & 15);
      const float bv = bias[n];
      #pragma unroll
      for (int fm = 0; fm < 4; ++fm) {
        const int mb = m0 + wm + fm * 16 + ((lane >> 4) << 2);
        f32x4 v = acc[fm][fn];
        #pragma unroll
        for (int r = 0; r < 4; ++r)
          C[(size_t)(mb + r) * N_DIM + n] = v[r] + bv;
      }
    }
  } else {  // WMODE == 2: h rows bf16 at [n][tau], stride 2*NFFT u16
    u16* C = (u16*)Cv;
    #pragma unroll
    for (int fn = 0; fn < 4; ++fn) {
      const int n = n0 + wn + fn * 16 + (lane & 15);
      const float bv = bias[n];
      const float ad = fabsf(dk[n]);
      u16* row = C + (size_t)n * (2 * NFFT);
      #pragma unroll
      for (int fm = 0; fm < 4; ++fm) {
        const int mq = m0 + wm + fm * 16 + ((lane >> 4) << 2);
        f32x4 v = acc[fm][fn];
        U16x4 w;
        #pragma unroll
        for (int r = 0; r < 4; ++r) {
          const int t = mq + r;
          const float mt = (t < L_SEQ) ? (float)t * (1.0f / 8191.0f)
                                       : (float)(NFFT - 1 - t) * (1.0f / 8191.0f);
          const float dec = __expf(-mt * ad);
          ((u16*)&w)[r] = f2bf((v[r] + bv) * dec);
        }
        *(U16x4*)&row[mq] = w;
      }
    }
  }
}

// ===========================================================================
// Kernel B: PACKED filter spectra — one complex FFT per channel f computes
// both real filters' spectra:  Z = FFT(h0 + i*h1);
//   H0[k] = (Z[k]+conj(Z[-k]))/2,  H1[k] = (Z[k]-conj(Z[-k]))/(2i).
// Digit-reversed partner: k = rev4(p), pb = rev4((N-k) mod N).  Self-paired
// bins (k=0 -> p=0, k=N/2 -> p=2) satisfy the same formulas (b == a).
// ===========================================================================
__global__ __launch_bounds__(NT)
void filter_fft_kernel(float* __restrict__ hH, const float* __restrict__ bias)
{
  __shared__ float zr[NPAD];
  __shared__ float zi[NPAD];
  const int f = blockIdx.x;              // 0..F_DIM-1
  const int tid = threadIdx.x;
  float* row0 = hH + (size_t)f * NFFT;
  float* row1 = hH + (size_t)(F_DIM + f) * NFFT;
  const u16* h0 = (const u16*)row0;
  const u16* h1 = (const u16*)row1;

  for (int t = tid; t < NFFT; t += NT) {
    zr[PAD(t)] = bf2f(h0[t]);
    zi[PAD(t)] = bf2f(h1[t]);
  }
  __syncthreads();
  fwd_pairs<12>(zr, zi, tid);
  // final twiddle-free radix-4 (verbatim round-0 tail), in place
  for (int b = tid; b < NFFT / 4; b += NT) {
    const int p = PAD(b << 2);
    const float a0r = zr[p],     a0i = zi[p];
    const float a1r = zr[p + 1], a1i = zi[p + 1];
    const float a2r = zr[p + 2], a2i = zi[p + 2];
    const float a3r = zr[p + 3], a3i = zi[p + 3];
    const float t0r = a0r + a2r, t0i = a0i + a2i;
    const float t1r = a0r - a2r, t1i = a0i - a2i;
    const float t2r = a1r + a3r, t2i = a1i + a3i;
    const float t3r = a1r - a3r, t3i = a1i - a3i;
    zr[p]     = t0r + t2r; zi[p]     = t0i + t2i;
    zr[p + 1] = t1r + t3i; zi[p + 1] = t1i - t3r;
    zr[p + 2] = t0r - t2r; zi[p + 2] = t0i - t2i;
    zr[p + 3] = t1r - t3i; zi[p + 3] = t1i + t3r;
  }
  __syncthreads();
  // untangle + scale + bias-fold; writes coalesced at p, partner read scattered
  const float bo0 = bias[f];
  const float bo1 = bias[F_DIM + f];
  const float s = 1.0f / (float)NFFT;
  __hip_bfloat162* o0 = (__hip_bfloat162*)row0;
  __hip_bfloat162* o1 = (__hip_bfloat162*)row1;
  for (int p = tid; p < NFFT; p += NT) {
    const int k  = rev4_14(p);
    const int pb = rev4_14((NFFT - k) & (NFFT - 1));
    const float ar = zr[PAD(p)],  ai = zi[PAD(p)];
    const float br = zr[PAD(pb)], bi = zi[PAD(pb)];
    const float h0r = 0.5f * (ar + br), h0i = 0.5f * (ai - bi);
    const float h1r = 0.5f * (ai + bi), h1i = 0.5f * (br - ar);
    __hip_bfloat162 w0, w1;
    w0.x = __float2bfloat16((h0r + bo0) * s); w0.y = __float2bfloat16(h0i * s);
    w1.x = __float2bfloat16((h1r + bo1) * s); w1.y = __float2bfloat16(h1i * s);
    o0[p] = w0; o1[p] = w1;
  }
}

// ===========================================================================
// Kernel C: fused shortconv + 2x (FFT conv + gate) — unchanged from round 8.
// ===========================================================================
__global__ __launch_bounds__(NT)
void fftconv_kernel(const u16* __restrict__ up, float* __restrict__ hH,
                    const float* __restrict__ sw, const float* __restrict__ sb)
{
  __shared__ float zr[NPAD];
  __shared__ float zi[NPAD];
  const int f = blockIdx.x;
  const int tid = threadIdx.x;
  float* rowf = hH + (size_t)f * NFFT;            // o=0 spectra; later v01 out
  float* row1 = hH + (size_t)(F_DIM + f) * NFFT;  // o=1 spectra

  const u16* u0 = up + (size_t)(0 * C_IN + f) * L_SEQ;
  const u16* u1 = up + (size_t)(1 * C_IN + f) * L_SEQ;
  const float vw0 = sw[f], vw1 = sw[C_IN + f], vw2 = sw[2 * C_IN + f];
  const float vb = sb[f];

  // ===== o = 0 =====
  for (int g = tid; g < 1024; g += NT) {
    float xr[2][4], xi[2][4];
    #pragma unroll
    for (int k = 0; k < 2; ++k)
      #pragma unroll
      for (int m = 0; m < 4; ++m) {
        const int t = g + (m << 10) + (k << 12);
        xr[k][m] = conv3b(u0, t, vw0, vw1, vw2, vb);
        xi[k][m] = conv3b(u1, t, vw0, vw1, vw2, vb);
      }
    s1_zero_hi(zr, zi, g, xr, xi);
  }
  __syncthreads();
  fwd_pairs<8>(zr, zi, tid);
  fused_final_spec_head(zr, zi, (const __hip_bfloat162*)rowf, tid);
  inv_mid_pairs(zr, zi, tid);

  const int c0g = F_DIM + f;
  inv_last_gate<false>(zr, zi,
      up + (size_t)(0 * C_IN + c0g) * L_SEQ,
      up + (size_t)(1 * C_IN + c0g) * L_SEQ,
      sw[c0g], sw[C_IN + c0g], sw[2 * C_IN + c0g], sb[c0g], nullptr, tid);

  // ===== o = 1 ===== (input = gated o=0 result, t<8192 in LDS)
  for (int g = tid; g < 1024; g += NT) {
    float xr[2][4], xi[2][4];
    #pragma unroll
    for (int k = 0; k < 2; ++k)
      #pragma unroll
      for (int m = 0; m < 4; ++m) {
        const int idx = PAD(g + (m << 10) + (k << 12));
        xr[k][m] = zr[idx]; xi[k][m] = zi[idx];
      }
    s1_zero_hi(zr, zi, g, xr, xi);
  }
  __syncthreads();
  fwd_pairs<8>(zr, zi, tid);
  fused_final_spec_head(zr, zi, (const __hip_bfloat162*)row1, tid);
  inv_mid_pairs(zr, zi, tid);

  const int c1g = 2 * F_DIM + f;
  inv_last_gate<true>(zr, zi,
      up + (size_t)(0 * C_IN + c1g) * L_SEQ,
      up + (size_t)(1 * C_IN + c1g) * L_SEQ,
      sw[c1g], sw[C_IN + c1g], sw[2 * C_IN + c1g], sb[c1g], (u16*)rowf, tid);
}

// ===========================================================================
extern "C" void kernel_launch(void* const* d_in, const int* in_sizes, int n_in,
                              void* d_out, int out_size, void* d_ws, size_t ws_size,
                              hipStream_t stream)
{
  (void)in_sizes; (void)n_in; (void)out_size; (void)ws_size;
  const float* u     = (const float*)d_in[0];
  const float* fw1   = (const float*)d_in[1];
  const float* fb1   = (const float*)d_in[2];
  const float* fw2   = (const float*)d_in[3];
  const float* fb2   = (const float*)d_in[4];
  const float* decay = (const float*)d_in[5];
  const float* bias  = (const float*)d_in[6];
  const float* ipw   = (const float*)d_in[7];
  const float* ipb   = (const float*)d_in[8];
  const float* sw    = (const float*)d_in[9];
  const float* sb    = (const float*)d_in[10];
  const float* ow    = (const float*)d_in[11];
  const float* ob    = (const float*)d_in[12];
  float* out = (float*)d_out;

  char* ws = (char*)d_ws;
  u16*   up_t  = (u16*)(ws);                                // 75,497,472 B
  float* hH    = (float*)(ws + 75497472);                   // 100,663,296 B
  u16*   u_bf  = (u16*)(ws + 176160768);                    // 25,165,824 B
  u16*   ipw_t = (u16*)(ws + 201326592);                    // 3,538,944 B
  u16*   ow_t  = (u16*)(ws + 204865536);                    // 1,179,648 B
  // filter-path scratch in the up_t region (dead until gemm1 runs later):
  u16*   hidb  = (u16*)(ws);                                // 2,097,152 B
  u16*   w2t   = (u16*)(ws + 2097152);                      //   196,608 B

  cast_bf16_kernel<<<dim3(12288), 256, 0, stream>>>(u, u_bf, (2 * L_SEQ * D_DIM) / 4);
  transpose_cast_kernel<<<dim3(C_IN / 32, D_DIM / 32), 256, 0, stream>>>(ipw, ipw_t, D_DIM, C_IN);
  transpose_cast_kernel<<<dim3(D_DIM / 32, F_DIM / 32), 256, 0, stream>>>(ow, ow_t, F_DIM, D_DIM);

  // filter path: hid (bf16) -> w2^T (bf16) -> MFMA h-GEMM (+decay epilogue)
  // -> packed FFT (one per channel, both orders)
  hid_gen_kernel<<<dim3(NFFT / 16), 256, 0, stream>>>(fw1, fb1, hidb);
  transpose_cast_kernel<<<dim3(1536 / 32, 64 / 32), 256, 0, stream>>>(fw2, w2t, 64, 1536);
  mfma_gemm_kernel<1536, 64, 2><<<dim3(NFFT / 128, 1536 / 128), 256, 0, stream>>>(
      hidb, w2t, fb2, hH, decay);
  filter_fft_kernel<<<dim3(F_DIM), NT, 0, stream>>>(hH, bias);

  mfma_gemm_kernel<C_IN, D_DIM, 0><<<dim3(128, C_IN / 128), 256, 0, stream>>>(u_bf, ipw_t, ipb, up_t, nullptr);
  fftconv_kernel<<<dim3(F_DIM), NT, 0, stream>>>(up_t, hH, sw, sb);
  // gemm2 reads v01 rows (u16 [f][m], stride 2*NFFT) with fused transpose
  mfma_gemm_kernel<D_DIM, F_DIM, 1, 1, 2 * NFFT><<<dim3(128, D_DIM / 128), 256, 0, stream>>>(
      (const u16*)hH, ow_t, ob, out, nullptr);
}

// Round 11
// 504.428 us; speedup vs baseline: 1.0140x; 1.0140x over previous
//
#include <hip/hip_runtime.h>
#include <hip/hip_bf16.h>
#include <math.h>

#define L_SEQ 8192
#define NFFT  16384
#define NPAD  16896   // NFFT + NFFT/32 padding (floats per array)
#define F_DIM 768
#define D_DIM 768
#define C_IN  2304    // INNER = F*(ORDER+1)
#define NORD  2
#define NT    512
#define TWO_PI 6.2831853071795864769f
// cos/sin(2*pi/16): per-m twiddle step in all 4-angle layers
#define C16 0.92387953251128675613f
#define S16 0.38268343236508977172f

typedef unsigned short u16;
typedef __attribute__((ext_vector_type(8))) short bf16x8;
typedef __attribute__((ext_vector_type(4))) float f32x4;
struct __align__(8) U16x4 { u16 x, y, z, w; };

__device__ __forceinline__ float bf2f(u16 v) {
  unsigned u = ((unsigned)v) << 16; float f; __builtin_memcpy(&f, &u, 4); return f;
}
__device__ __forceinline__ u16 f2bf(float f) {
  __hip_bfloat16 h = __float2bfloat16(f); u16 r; __builtin_memcpy(&r, &h, 2); return r;
}

// LDS pad: bank(i) shifts by 1 every 32 floats -> all FFT strides <=2-way (free).
// NOTE: pad stride 1 breaks 8/16B alignment classes -> LDS access must stay b32.
__device__ __forceinline__ int PAD(int i) { return i + (i >> 5); }

// reverse the 7 base-4 digits of a 14-bit index (DIF output permutation: k = rev4(p))
__device__ __forceinline__ int rev4_14(int p) {
  return ((p & 0x0003) << 12) | ((p & 0x000C) << 8) | ((p & 0x0030) << 4)
       | ( p & 0x00C0       ) | ((p & 0x0300) >> 4) | ((p & 0x0C00) >> 8)
       | ((p & 0x3000) >> 12);
}

__device__ __forceinline__ void rot3(float ang, float& c1, float& s1,
                                     float& c2, float& s2, float& c3, float& s3)
{
  __sincosf(ang, &s1, &c1);
  c2 = c1 * c1 - s1 * s1; s2 = 2.0f * c1 * s1;
  c3 = c1 * c2 - s1 * s2; s3 = c1 * s2 + s1 * c2;
}

// advance (c,s) by angle -2pi/16 (fwd stages) / +2pi/16 (inv stages)
__device__ __forceinline__ void adv_fwd(float& c, float& s) {
  const float cn = c * C16 + s * S16;
  s = s * C16 - c * S16; c = cn;
}
__device__ __forceinline__ void adv_inv(float& c, float& s) {
  const float cn = c * C16 - s * S16;
  s = s * C16 + c * S16; c = cn;
}

// depthwise conv3 on a bf16 row, SAME padding (XLA cross-correlation)
__device__ __forceinline__ float conv3b(const u16* __restrict__ row, int t,
                                        float w0, float w1, float w2, float sb)
{
  float l = (t > 0)         ? bf2f(row[t - 1]) : 0.0f;
  float c = bf2f(row[t]);
  float r = (t < L_SEQ - 1) ? bf2f(row[t + 1]) : 0.0f;
  return w0 * l + w1 * c + w2 * r + sb;
}

// ===========================================================================
// Radix-4 FFT, N = 16384 = 4^7, PLANAR zr/zi in LDS (b32, 2-way-free PAD).
// Stage algebra verbatim from the verified round-0/round-7 kernels; the only
// change (this round) is deriving the 4 related twiddles per layer from ONE
// sincos via constant rotation by -/+2pi/16 (exact same angles, ~1e-7 drift).
// ===========================================================================

// layer-2 (stage 10) + planar stores of the first fwd pair. g in [0,1024).
__device__ __forceinline__ void s1_l2_store(float* zr, float* zi, int g,
    const float yr[4][4], const float yi4[4][4])
{
  const float stw2 = -TWO_PI / 4096.0f;
  float c1, s1, c2, s2, c3, s3;
  rot3(stw2 * (float)g, c1, s1, c2, s2, c3, s3);
  #pragma unroll
  for (int k = 0; k < 4; ++k) {
    float t0r = yr[k][0] + yr[k][2], t0i = yi4[k][0] + yi4[k][2];
    float t1r = yr[k][0] - yr[k][2], t1i = yi4[k][0] - yi4[k][2];
    float t2r = yr[k][1] + yr[k][3], t2i = yi4[k][1] + yi4[k][3];
    float t3r = yr[k][1] - yr[k][3], t3i = yi4[k][1] - yi4[k][3];
    float o0r = t0r + t2r, o0i = t0i + t2i;
    float o1r = t1r + t3i, o1i = t1i - t3r;
    float o2r = t0r - t2r, o2i = t0i - t2i;
    float o3r = t1r - t3i, o3i = t1i + t3r;
    const int i0 = g + (k << 12);
    zr[PAD(i0       )] = o0r;               zi[PAD(i0       )] = o0i;
    zr[PAD(i0 + 1024)] = o1r*c1 - o1i*s1;   zi[PAD(i0 + 1024)] = o1r*s1 + o1i*c1;
    zr[PAD(i0 + 2048)] = o2r*c2 - o2i*s2;   zi[PAD(i0 + 2048)] = o2r*s2 + o2i*c2;
    zr[PAD(i0 + 3072)] = o3r*c3 - o3i*s3;   zi[PAD(i0 + 3072)] = o3r*s3 + o3i*c3;
  }
}

// stage-1 layer-1 with k=2,3 inputs == 0 (zero-padded upper half).
// Angles: stw1*(g + m*1024), step = -2pi/16 -> derived by adv_fwd.
__device__ __forceinline__ void s1_zero_hi(float* zr, float* zi, int g,
    const float xr[2][4], const float xi[2][4])
{
  const float stw1 = -TWO_PI / 16384.0f;
  float yr[4][4], yi4[4][4];
  float c1, s1;
  __sincosf(stw1 * (float)g, &s1, &c1);
  #pragma unroll
  for (int m = 0; m < 4; ++m) {
    const float x0r = xr[0][m], x0i = xi[0][m];
    const float x1r = xr[1][m], x1i = xi[1][m];
    const float y0r = x0r + x1r, y0i = x0i + x1i;
    const float y1r = x0r + x1i, y1i = x0i - x1r;
    const float y2r = x0r - x1r, y2i = x0i - x1i;
    const float y3r = x0r - x1i, y3i = x0i + x1r;
    const float c2 = c1*c1 - s1*s1, s2 = 2.0f*c1*s1;
    const float c3 = c1*c2 - s1*s2, s3 = c1*s2 + s1*c2;
    yr[0][m] = y0r;               yi4[0][m] = y0i;
    yr[1][m] = y1r*c1 - y1i*s1;   yi4[1][m] = y1r*s1 + y1i*c1;
    yr[2][m] = y2r*c2 - y2i*s2;   yi4[2][m] = y2r*s2 + y2i*c2;
    yr[3][m] = y3r*c3 - y3i*s3;   yi4[3][m] = y3r*s3 + y3i*c3;
    adv_fwd(c1, s1);
  }
  s1_l2_store(zr, zi, g, yr, yi4);
}

// fwd pairs (lq, lq-2) down to (4,2) — planar body verbatim from round 0;
// layer-1 twiddles derived (step stw1*q4 = -2pi/16).
template<int LQ0>
__device__ __forceinline__ void fwd_pairs(float* zr, float* zi, int tid)
{
  #pragma unroll
  for (int lq = LQ0; lq >= 4; lq -= 4) {
    const int q  = 1 << lq;
    const int q4 = q >> 2;
    const float stw1 = -TWO_PI / (float)(q << 2);
    const float stw2 = -TWO_PI / (float)q;
    for (int g = tid; g < NFFT / 16; g += NT) {
      const int j    = g & (q4 - 1);
      const int base = ((g >> (lq - 2)) << (lq + 2)) + j;
      float xr[4][4], xi4[4][4];
      #pragma unroll
      for (int k = 0; k < 4; ++k)
        #pragma unroll
        for (int m = 0; m < 4; ++m) {
          const int idx = PAD(base + m * q4 + k * q);
          xr[k][m] = zr[idx]; xi4[k][m] = zi[idx];
        }
      float c1a, s1a;
      __sincosf(stw1 * (float)j, &s1a, &c1a);
      #pragma unroll
      for (int m = 0; m < 4; ++m) {
        float t0r = xr[0][m] + xr[2][m], t0i = xi4[0][m] + xi4[2][m];
        float t1r = xr[0][m] - xr[2][m], t1i = xi4[0][m] - xi4[2][m];
        float t2r = xr[1][m] + xr[3][m], t2i = xi4[1][m] + xi4[3][m];
        float t3r = xr[1][m] - xr[3][m], t3i = xi4[1][m] - xi4[3][m];
        float y0r = t0r + t2r, y0i = t0i + t2i;
        float y1r = t1r + t3i, y1i = t1i - t3r;
        float y2r = t0r - t2r, y2i = t0i - t2i;
        float y3r = t1r - t3i, y3i = t1i + t3r;
        const float c2 = c1a*c1a - s1a*s1a, s2 = 2.0f*c1a*s1a;
        const float c3 = c1a*c2 - s1a*s2, s3 = c1a*s2 + s1a*c2;
        xr[0][m] = y0r;                  xi4[0][m] = y0i;
        xr[1][m] = y1r * c1a - y1i * s1a; xi4[1][m] = y1r * s1a + y1i * c1a;
        xr[2][m] = y2r * c2 - y2i * s2;   xi4[2][m] = y2r * s2 + y2i * c2;
        xr[3][m] = y3r * c3 - y3i * s3;   xi4[3][m] = y3r * s3 + y3i * c3;
        adv_fwd(c1a, s1a);
      }
      float c1, s1, c2, s2, c3, s3;
      rot3(stw2 * (float)j, c1, s1, c2, s2, c3, s3);
      #pragma unroll
      for (int k = 0; k < 4; ++k) {
        float t0r = xr[k][0] + xr[k][2], t0i = xi4[k][0] + xi4[k][2];
        float t1r = xr[k][0] - xr[k][2], t1i = xi4[k][0] - xi4[k][2];
        float t2r = xr[k][1] + xr[k][3], t2i = xi4[k][1] + xi4[k][3];
        float t3r = xr[k][1] - xr[k][3], t3i = xi4[k][1] - xi4[k][3];
        float y0r = t0r + t2r, y0i = t0i + t2i;
        float y1r = t1r + t3i, y1i = t1i - t3r;
        float y2r = t0r - t2r, y2i = t0i - t2i;
        float y3r = t1r - t3i, y3i = t1i + t3r;
        const int i0 = base + k * q;
        zr[PAD(i0         )] = y0r;            zi[PAD(i0         )] = y0i;
        zr[PAD(i0 +     q4)] = y1r*c1 - y1i*s1; zi[PAD(i0 +     q4)] = y1r*s1 + y1i*c1;
        zr[PAD(i0 + 2 * q4)] = y2r*c2 - y2i*s2; zi[PAD(i0 + 2 * q4)] = y2r*s2 + y2i*c2;
        zr[PAD(i0 + 3 * q4)] = y3r*c3 - y3i*s3; zi[PAD(i0 + 3 * q4)] = y3r*s3 + y3i*c3;
      }
    }
    __syncthreads();
  }
}

// fwd final radix-4 + spectrum multiply + inv head fused in registers (b32 LDS).
__device__ __forceinline__ void fused_final_spec_head(float* zr, float* zi,
    const __hip_bfloat162* __restrict__ H, int tid)
{
  for (int b = tid; b < NFFT / 4; b += NT) {
    const int i0 = b << 2;
    const int p  = PAD(i0);                  // quad never crosses pad stripe
    const float a0r = zr[p],     a0i = zi[p];
    const float a1r = zr[p + 1], a1i = zi[p + 1];
    const float a2r = zr[p + 2], a2i = zi[p + 2];
    const float a3r = zr[p + 3], a3i = zi[p + 3];
    float t0r = a0r + a2r, t0i = a0i + a2i;
    float t1r = a0r - a2r, t1i = a0i - a2i;
    float t2r = a1r + a3r, t2i = a1i + a3i;
    float t3r = a1r - a3r, t3i = a1i - a3i;
    float y0r = t0r + t2r, y0i = t0i + t2i;
    float y1r = t1r + t3i, y1i = t1i - t3r;
    float y2r = t0r - t2r, y2i = t0i - t2i;
    float y3r = t1r - t3i, y3i = t1i + t3r;
    const float4 hq = *(const float4*)&H[i0];
    __hip_bfloat162 h0, h1, h2, h3;
    __builtin_memcpy(&h0, &hq.x, 4); __builtin_memcpy(&h1, &hq.y, 4);
    __builtin_memcpy(&h2, &hq.z, 4); __builtin_memcpy(&h3, &hq.w, 4);
    float hr, hi;
    hr = __bfloat162float(h0.x); hi = __bfloat162float(h0.y);
    const float u0r = y0r*hr - y0i*hi, u0i = y0r*hi + y0i*hr;
    hr = __bfloat162float(h1.x); hi = __bfloat162float(h1.y);
    const float u1r = y1r*hr - y1i*hi, u1i = y1r*hi + y1i*hr;
    hr = __bfloat162float(h2.x); hi = __bfloat162float(h2.y);
    const float u2r = y2r*hr - y2i*hi, u2i = y2r*hi + y2i*hr;
    hr = __bfloat162float(h3.x); hi = __bfloat162float(h3.y);
    const float u3r = y3r*hr - y3i*hi, u3i = y3r*hi + y3i*hr;
    const float e0r = u0r + u2r, e0i = u0i + u2i;
    const float e1r = u0r - u2r, e1i = u0i - u2i;
    const float f0r = u1r + u3r, f0i = u1i + u3i;
    const float f1r = u1r - u3r, f1i = u1i - u3i;
    zr[p]     = e0r + f0r; zi[p]     = e0i + f0i;
    zr[p + 1] = e1r - f1i; zi[p + 1] = e1i + f1r;
    zr[p + 2] = e0r - f0r; zi[p + 2] = e0i - f0i;
    zr[p + 3] = e1r + f1i; zi[p + 3] = e1i - f1r;
  }
  __syncthreads();
}

// inv middle pairs (2,4)(6,8) — planar body verbatim from round 0;
// layer-2 twiddles derived (step stw2*q = +2pi/16).
__device__ __forceinline__ void inv_mid_pairs(float* zr, float* zi, int tid)
{
  #pragma unroll
  for (int lq = 2; lq <= 6; lq += 4) {
    const int q = 1 << lq;
    const int Q = q << 2;
    const float stw1 = TWO_PI / (float)(q << 2);
    const float stw2 = TWO_PI / (float)(Q << 2);
    for (int g = tid; g < NFFT / 16; g += NT) {
      const int j    = g & (q - 1);
      const int base = ((g >> lq) << (lq + 4)) + j;
      float xr[4][4], xi4[4][4];
      #pragma unroll
      for (int k = 0; k < 4; ++k)
        #pragma unroll
        for (int m = 0; m < 4; ++m) {
          const int idx = PAD(base + m * q + k * Q);
          xr[k][m] = zr[idx]; xi4[k][m] = zi[idx];
        }
      {
        float c1, s1, c2, s2, c3, s3;
        rot3(stw1 * (float)j, c1, s1, c2, s2, c3, s3);
        #pragma unroll
        for (int k = 0; k < 4; ++k) {
          float u0r = xr[k][0], u0i = xi4[k][0];
          float u1r = xr[k][1]*c1 - xi4[k][1]*s1, u1i = xr[k][1]*s1 + xi4[k][1]*c1;
          float u2r = xr[k][2]*c2 - xi4[k][2]*s2, u2i = xr[k][2]*s2 + xi4[k][2]*c2;
          float u3r = xr[k][3]*c3 - xi4[k][3]*s3, u3i = xr[k][3]*s3 + xi4[k][3]*c3;
          float e0r = u0r + u2r, e0i = u0i + u2i;
          float e1r = u0r - u2r, e1i = u0i - u2i;
          float f0r = u1r + u3r, f0i = u1i + u3i;
          float f1r = u1r - u3r, f1i = u1i - u3i;
          xr[k][0] = e0r + f0r; xi4[k][0] = e0i + f0i;
          xr[k][1] = e1r - f1i; xi4[k][1] = e1i + f1r;
          xr[k][2] = e0r - f0r; xi4[k][2] = e0i - f0i;
          xr[k][3] = e1r + f1i; xi4[k][3] = e1i - f1r;
        }
      }
      float c1b, s1b;
      __sincosf(stw2 * (float)j, &s1b, &c1b);
      #pragma unroll
      for (int m = 0; m < 4; ++m) {
        const float c2 = c1b*c1b - s1b*s1b, s2 = 2.0f*c1b*s1b;
        const float c3 = c1b*c2 - s1b*s2, s3 = c1b*s2 + s1b*c2;
        float u0r = xr[0][m], u0i = xi4[0][m];
        float u1r = xr[1][m]*c1b - xi4[1][m]*s1b, u1i = xr[1][m]*s1b + xi4[1][m]*c1b;
        float u2r = xr[2][m]*c2 - xi4[2][m]*s2, u2i = xr[2][m]*s2 + xi4[2][m]*c2;
        float u3r = xr[3][m]*c3 - xi4[3][m]*s3, u3i = xr[3][m]*s3 + xi4[3][m]*c3;
        float e0r = u0r + u2r, e0i = u0i + u2i;
        float e1r = u0r - u2r, e1i = u0i - u2i;
        float f0r = u1r + u3r, f0i = u1i + u3i;
        float f1r = u1r - u3r, f1i = u1i - u3i;
        const int i0 = base + m * q;
        zr[PAD(i0        )] = e0r + f0r; zi[PAD(i0        )] = e0i + f0i;
        zr[PAD(i0 +     Q)] = e1r - f1i; zi[PAD(i0 +     Q)] = e1i + f1r;
        zr[PAD(i0 + 2 * Q)] = e0r - f0r; zi[PAD(i0 + 2 * Q)] = e0i - f0i;
        zr[PAD(i0 + 3 * Q)] = e1r + f1i; zi[PAD(i0 + 3 * Q)] = e1i - f1r;
        adv_inv(c1b, s1b);
      }
    }
    __syncthreads();
  }
}

// inv last pair (10,12) fused with gate; outputs only t<8192 (k=0,1).
// layer-2 twiddles derived (step stw2*1024 = +2pi/16).
template<bool TO_GLOBAL>
__device__ __forceinline__ void inv_last_gate(float* zr, float* zi,
    const u16* __restrict__ gr0, const u16* __restrict__ gr1,
    float w0, float w1, float w2, float wb, u16* __restrict__ outv, int tid)
{
  const float stw1 = TWO_PI / 4096.0f;    // 2pi/(4q), q=1024
  const float stw2 = TWO_PI / 16384.0f;   // 2pi/(4Q), Q=4096
  for (int g = tid; g < 1024; g += NT) {
    float xr[4][4], xi4[4][4];
    #pragma unroll
    for (int k = 0; k < 4; ++k)
      #pragma unroll
      for (int m = 0; m < 4; ++m) {
        const int idx = PAD(g + (m << 10) + (k << 12));
        xr[k][m] = zr[idx]; xi4[k][m] = zi[idx];
      }
    {                                      // layer 1: stage 10, j1 = g
      float c1, s1, c2, s2, c3, s3;
      rot3(stw1 * (float)g, c1, s1, c2, s2, c3, s3);
      #pragma unroll
      for (int k = 0; k < 4; ++k) {
        float u0r = xr[k][0], u0i = xi4[k][0];
        float u1r = xr[k][1]*c1 - xi4[k][1]*s1, u1i = xr[k][1]*s1 + xi4[k][1]*c1;
        float u2r = xr[k][2]*c2 - xi4[k][2]*s2, u2i = xr[k][2]*s2 + xi4[k][2]*c2;
        float u3r = xr[k][3]*c3 - xi4[k][3]*s3, u3i = xr[k][3]*s3 + xi4[k][3]*c3;
        float e0r = u0r + u2r, e0i = u0i + u2i;
        float e1r = u0r - u2r, e1i = u0i - u2i;
        float f0r = u1r + u3r, f0i = u1i + u3i;
        float f1r = u1r - u3r, f1i = u1i - u3i;
        xr[k][0] = e0r + f0r; xi4[k][0] = e0i + f0i;
        xr[k][1] = e1r - f1i; xi4[k][1] = e1i + f1r;
        xr[k][2] = e0r - f0r; xi4[k][2] = e0i - f0i;
        xr[k][3] = e1r + f1i; xi4[k][3] = e1i - f1r;
      }
    }
    float c1L, s1L;
    __sincosf(stw2 * (float)g, &s1L, &c1L);
    #pragma unroll
    for (int m = 0; m < 4; ++m) {          // layer 2: stage 12, j2 = g + m*1024
      const float c2 = c1L*c1L - s1L*s1L, s2 = 2.0f*c1L*s1L;
      const float c3 = c1L*c2 - s1L*s2, s3 = c1L*s2 + s1L*c2;
      float u0r = xr[0][m], u0i = xi4[0][m];
      float u1r = xr[1][m]*c1L - xi4[1][m]*s1L, u1i = xr[1][m]*s1L + xi4[1][m]*c1L;
      float u2r = xr[2][m]*c2 - xi4[2][m]*s2, u2i = xr[2][m]*s2 + xi4[2][m]*c2;
      float u3r = xr[3][m]*c3 - xi4[3][m]*s3, u3i = xr[3][m]*s3 + xi4[3][m]*c3;
      float e0r = u0r + u2r, e0i = u0i + u2i;
      float e1r = u0r - u2r, e1i = u0i - u2i;
      float f0r = u1r + u3r, f0i = u1i + u3i;
      float f1r = u1r - u3r, f1i = u1i - u3i;
      const int t0 = g + (m << 10);        // k=0 output, t0 < 4096
      const int t1 = t0 + 4096;            // k=1 output, t1 < 8192
      const float o0r = e0r + f0r, o0i = e0i + f0i;
      const float o1r = e1r - f1i, o1i = e1i + f1r;
      const float a0 = conv3b(gr0, t0, w0, w1, w2, wb);
      const float b0 = conv3b(gr1, t0, w0, w1, w2, wb);
      const float a1 = conv3b(gr0, t1, w0, w1, w2, wb);
      const float b1 = conv3b(gr1, t1, w0, w1, w2, wb);
      if (TO_GLOBAL) {
        outv[t0]         = f2bf(o0r * a0);
        outv[L_SEQ + t0] = f2bf(o0i * b0);
        outv[t1]         = f2bf(o1r * a1);
        outv[L_SEQ + t1] = f2bf(o1i * b1);
      } else {
        zr[PAD(t0)] = o0r * a0;  zi[PAD(t0)] = o0i * b0;
        zr[PAD(t1)] = o1r * a1;  zi[PAD(t1)] = o1i * b1;
      }
      adv_inv(c1L, s1L);
      // k=2,3 outputs (t >= 8192) are never needed: not written.
    }
  }
  if (!TO_GLOBAL) __syncthreads();
}

// ===========================================================================
// Prep kernels
// ===========================================================================
__global__ __launch_bounds__(256)
void cast_bf16_kernel(const float* __restrict__ in, u16* __restrict__ out, int n4)
{
  int i = blockIdx.x * 256 + threadIdx.x;
  if (i < n4) {
    float4 v = ((const float4*)in)[i];
    U16x4 w; w.x = f2bf(v.x); w.y = f2bf(v.y); w.z = f2bf(v.z); w.w = f2bf(v.w);
    ((U16x4*)out)[i] = w;
  }
}

__global__ __launch_bounds__(256)
void transpose_cast_kernel(const float* __restrict__ in, u16* __restrict__ out,
                           int K, int N)   // in [K][N] fp32 -> out [N][K] bf16
{
  __shared__ u16 tile[32][33];
  const int n0 = blockIdx.x * 32, k0 = blockIdx.y * 32;
  const int tx = threadIdx.x & 31, ty = threadIdx.x >> 5;
  #pragma unroll
  for (int i = 0; i < 32; i += 8)
    tile[ty + i][tx] = f2bf(in[(size_t)(k0 + ty + i) * N + n0 + tx]);
  __syncthreads();
  #pragma unroll
  for (int i = 0; i < 32; i += 8)
    out[(size_t)(n0 + ty + i) * K + k0 + tx] = tile[tx][ty + i];
}

// hid[16384][64] bf16: first MLP layer on the sine positional embedding.
__global__ __launch_bounds__(256)
void hid_gen_kernel(const float* __restrict__ w1, const float* __restrict__ b1,
                    u16* __restrict__ hidb)
{
  const int tid = threadIdx.x;
  const int r  = tid & 63;
  const int tb = tid >> 6;
  const float w1v0 = w1[r];
  const float b1v  = b1[r];
  float w1c[4], w1s[4];
  #pragma unroll
  for (int p = 0; p < 4; ++p) { w1c[p] = w1[(1 + p) * 64 + r]; w1s[p] = w1[(5 + p) * 64 + r]; }
  const int tau0 = blockIdx.x * 16;
  #pragma unroll
  for (int i = 0; i < 4; ++i) {
    const int tau = tau0 + tb + i * 4;
    const float off = (tau < L_SEQ) ? (float)tau : (float)(tau - NFFT);
    float acc = b1v + off * (1.0f / 8192.0f) * w1v0;
    #pragma unroll
    for (int p = 0; p < 4; ++p) {
      const double period = 4.0 + (8188.0 * p) / 3.0;
      const float freq = (float)(6.283185307179586476925287 / period);
      float sp, cp;
      sincosf(off * freq, &sp, &cp);
      acc += cp * w1c[p] + sp * w1s[p];
    }
    hidb[(size_t)tau * 64 + r] = f2bf(sinf(acc));
  }
}

// ===========================================================================
// MFMA GEMM.  WMODE 0: up_t bf16 batch layout.  WMODE 1: fp32 [M][N].
// WMODE 2: filter h path (bf16 rows strided 2*NFFT; decay epilogue).
// ATRANS 1: A is u16 [k][m] rows with row stride ASTR; staged transposed via
//           paired-k b32 LDS writes (fuses the v transpose, bank-clean).
// GSWAP 1: blockIdx.y carries m, blockIdx.x carries n -> consecutive blocks
//          share the A panel (L2-resident) and re-read only the small B.
// ===========================================================================
template<int N_DIM, int K_DIM, int WMODE, int ATRANS = 0, int ASTR = 0, int GSWAP = 0>
__global__ __launch_bounds__(256)
void mfma_gemm_kernel(const u16* __restrict__ A, const u16* __restrict__ B,
                      const float* __restrict__ bias, void* __restrict__ Cv,
                      const float* __restrict__ dk)
{
  constexpr int BK = 64;
  __shared__ u16 As[128 * BK];
  __shared__ u16 Bs[128 * BK];
  const int tid  = threadIdx.x;
  const int lane = tid & 63;
  const int wid  = tid >> 6;
  const int m0 = (GSWAP ? blockIdx.y : blockIdx.x) * 128;
  const int n0 = (GSWAP ? blockIdx.x : blockIdx.y) * 128;

  const u16* aPtr[4]; const u16* bPtr[4];
  #pragma unroll
  for (int i = 0; i < 4; ++i) {
    const int g = tid + (i << 8);
    if (ATRANS == 0)
      aPtr[i] = A + (size_t)(m0 + (g >> 3)) * K_DIM + ((g & 7) << 3);
    bPtr[i] = B + (size_t)(n0 + (g >> 3)) * K_DIM + ((g & 7) << 3);
  }

  const int wm = (wid & 1) << 6;
  const int wn = (wid >> 1) << 6;
  int aoff[4], boff[4];
  #pragma unroll
  for (int f = 0; f < 4; ++f) {
    aoff[f] = (wm + f * 16 + (lane & 15)) * BK + ((lane >> 4) << 3);
    boff[f] = (wn + f * 16 + (lane & 15)) * BK + ((lane >> 4) << 3);
  }

  f32x4 acc[4][4];
  #pragma unroll
  for (int i = 0; i < 4; ++i)
    #pragma unroll
    for (int j = 0; j < 4; ++j)
      acc[i][j] = (f32x4){0.f, 0.f, 0.f, 0.f};

  for (int k0 = 0; k0 < K_DIM; k0 += BK) {
    if (ATRANS) {
      // A[m][k] = Arow[k][m]: load 16B chunks from k-row pairs, write b32
      // (two k per word).  Bank: b32 idx = (mc*8+q)*32 + kp -> kp spans all
      // 32 banks, 2 lanes/bank = free.
      #pragma unroll
      for (int i = 0; i < 2; ++i) {
        const int h  = tid + (i << 8);     // 0..511
        const int kp = h & 31;             // k-pair index
        const int mc = h >> 5;             // 0..15
        const uint4 v0 = *(const uint4*)&A[(size_t)(k0 + 2 * kp)     * ASTR + m0 + mc * 8];
        const uint4 v1 = *(const uint4*)&A[(size_t)(k0 + 2 * kp + 1) * ASTR + m0 + mc * 8];
        u16 e0[8], e1[8];
        __builtin_memcpy(e0, &v0, 16); __builtin_memcpy(e1, &v1, 16);
        #pragma unroll
        for (int q = 0; q < 8; ++q) {
          const unsigned pack = (unsigned)e0[q] | ((unsigned)e1[q] << 16);
          *(unsigned*)&As[(mc * 8 + q) * BK + 2 * kp] = pack;
        }
      }
    } else {
      #pragma unroll
      for (int i = 0; i < 4; ++i) {
        __builtin_amdgcn_global_load_lds(
            (const __attribute__((address_space(1))) void*)aPtr[i],
            (__attribute__((address_space(3))) void*)&As[(((wid << 6) + (i << 8)) << 3)],
            16, 0, 0);
        aPtr[i] += BK;
      }
    }
    #pragma unroll
    for (int i = 0; i < 4; ++i) {
      __builtin_amdgcn_global_load_lds(
          (const __attribute__((address_space(1))) void*)bPtr[i],
          (__attribute__((address_space(3))) void*)&Bs[(((wid << 6) + (i << 8)) << 3)],
          16, 0, 0);
      bPtr[i] += BK;
    }
    __syncthreads();
    #pragma unroll
    for (int kk = 0; kk < 2; ++kk) {
      bf16x8 af[4], bg[4];
      #pragma unroll
      for (int f = 0; f < 4; ++f) af[f] = *(const bf16x8*)&As[aoff[f] + kk * 32];
      #pragma unroll
      for (int f = 0; f < 4; ++f) bg[f] = *(const bf16x8*)&Bs[boff[f] + kk * 32];
      #pragma unroll
      for (int fm = 0; fm < 4; ++fm)
        #pragma unroll
        for (int fn = 0; fn < 4; ++fn)
          acc[fm][fn] = __builtin_amdgcn_mfma_f32_16x16x32_bf16(
              af[fm], bg[fn], acc[fm][fn], 0, 0, 0);
    }
    __syncthreads();
  }

  if (WMODE == 0) {
    u16* C = (u16*)Cv;
    const int b = m0 >> 13;
    const int tbase = (m0 & (L_SEQ - 1)) + wm + ((lane >> 4) << 2);
    #pragma unroll
    for (int fn = 0; fn < 4; ++fn) {
      const int n = n0 + wn + fn * 16 + (lane & 15);
      const float bv = bias[n];
      u16* row = C + ((size_t)b * N_DIM + n) * L_SEQ;
      #pragma unroll
      for (int fm = 0; fm < 4; ++fm) {
        f32x4 v = acc[fm][fn];
        U16x4 w;
        w.x = f2bf(v[0] + bv); w.y = f2bf(v[1] + bv);
        w.z = f2bf(v[2] + bv); w.w = f2bf(v[3] + bv);
        *(U16x4*)&row[tbase + fm * 16] = w;
      }
    }
  } else if (WMODE == 1) {
    float* C = (float*)Cv;
    #pragma unroll
    for (int fn = 0; fn < 4; ++fn) {
      const int n = n0 + wn + fn * 16 + (lane & 15);
      const float bv = bias[n];
      #pragma unroll
      for (int fm = 0; fm < 4; ++fm) {
        const int mb = m0 + wm + fm * 16 + ((lane >> 4) << 2);
        f32x4 v = acc[fm][fn];
        #pragma unroll
        for (int r = 0; r < 4; ++r)
          C[(size_t)(mb + r) * N_DIM + n] = v[r] + bv;
      }
    }
  } else {  // WMODE == 2: h rows bf16 at [n][tau], stride 2*NFFT u16
    u16* C = (u16*)Cv;
    #pragma unroll
    for (int fn = 0; fn < 4; ++fn) {
      const int n = n0 + wn + fn * 16 + (lane & 15);
      const float bv = bias[n];
      const float ad = fabsf(dk[n]);
      u16* row = C + (size_t)n * (2 * NFFT);
      #pragma unroll
      for (int fm = 0; fm < 4; ++fm) {
        const int mq = m0 + wm + fm * 16 + ((lane >> 4) << 2);
        f32x4 v = acc[fm][fn];
        U16x4 w;
        #pragma unroll
        for (int r = 0; r < 4; ++r) {
          const int t = mq + r;
          const float mt = (t < L_SEQ) ? (float)t * (1.0f / 8191.0f)
                                       : (float)(NFFT - 1 - t) * (1.0f / 8191.0f);
          const float dec = __expf(-mt * ad);
          ((u16*)&w)[r] = f2bf((v[r] + bv) * dec);
        }
        *(U16x4*)&row[mq] = w;
      }
    }
  }
}

// ===========================================================================
// Kernel B: PACKED filter spectra — one complex FFT per channel f computes
// both real filters' spectra:  Z = FFT(h0 + i*h1);
//   H0[k] = (Z[k]+conj(Z[-k]))/2,  H1[k] = (Z[k]-conj(Z[-k]))/(2i).
// Digit-reversed partner: k = rev4(p), pb = rev4((N-k) mod N).
// ===========================================================================
__global__ __launch_bounds__(NT)
void filter_fft_kernel(float* __restrict__ hH, const float* __restrict__ bias)
{
  __shared__ float zr[NPAD];
  __shared__ float zi[NPAD];
  const int f = blockIdx.x;              // 0..F_DIM-1
  const int tid = threadIdx.x;
  float* row0 = hH + (size_t)f * NFFT;
  float* row1 = hH + (size_t)(F_DIM + f) * NFFT;
  const u16* h0 = (const u16*)row0;
  const u16* h1 = (const u16*)row1;

  for (int t = tid; t < NFFT; t += NT) {
    zr[PAD(t)] = bf2f(h0[t]);
    zi[PAD(t)] = bf2f(h1[t]);
  }
  __syncthreads();
  fwd_pairs<12>(zr, zi, tid);
  // final twiddle-free radix-4 (verbatim round-0 tail), in place
  for (int b = tid; b < NFFT / 4; b += NT) {
    const int p = PAD(b << 2);
    const float a0r = zr[p],     a0i = zi[p];
    const float a1r = zr[p + 1], a1i = zi[p + 1];
    const float a2r = zr[p + 2], a2i = zi[p + 2];
    const float a3r = zr[p + 3], a3i = zi[p + 3];
    const float t0r = a0r + a2r, t0i = a0i + a2i;
    const float t1r = a0r - a2r, t1i = a0i - a2i;
    const float t2r = a1r + a3r, t2i = a1i + a3i;
    const float t3r = a1r - a3r, t3i = a1i - a3i;
    zr[p]     = t0r + t2r; zi[p]     = t0i + t2i;
    zr[p + 1] = t1r + t3i; zi[p + 1] = t1i - t3r;
    zr[p + 2] = t0r - t2r; zi[p + 2] = t0i - t2i;
    zr[p + 3] = t1r - t3i; zi[p + 3] = t1i + t3r;
  }
  __syncthreads();
  // untangle + scale + bias-fold; writes coalesced at p, partner read scattered
  const float bo0 = bias[f];
  const float bo1 = bias[F_DIM + f];
  const float s = 1.0f / (float)NFFT;
  __hip_bfloat162* o0 = (__hip_bfloat162*)row0;
  __hip_bfloat162* o1 = (__hip_bfloat162*)row1;
  for (int p = tid; p < NFFT; p += NT) {
    const int k  = rev4_14(p);
    const int pb = rev4_14((NFFT - k) & (NFFT - 1));
    const float ar = zr[PAD(p)],  ai = zi[PAD(p)];
    const float br = zr[PAD(pb)], bi = zi[PAD(pb)];
    const float h0r = 0.5f * (ar + br), h0i = 0.5f * (ai - bi);
    const float h1r = 0.5f * (ai + bi), h1i = 0.5f * (br - ar);
    __hip_bfloat162 w0, w1;
    w0.x = __float2bfloat16((h0r + bo0) * s); w0.y = __float2bfloat16(h0i * s);
    w1.x = __float2bfloat16((h1r + bo1) * s); w1.y = __float2bfloat16(h1i * s);
    o0[p] = w0; o1[p] = w1;
  }
}

// ===========================================================================
// Kernel C: fused shortconv + 2x (FFT conv + gate) — structure unchanged.
// ===========================================================================
__global__ __launch_bounds__(NT)
void fftconv_kernel(const u16* __restrict__ up, float* __restrict__ hH,
                    const float* __restrict__ sw, const float* __restrict__ sb)
{
  __shared__ float zr[NPAD];
  __shared__ float zi[NPAD];
  const int f = blockIdx.x;
  const int tid = threadIdx.x;
  float* rowf = hH + (size_t)f * NFFT;            // o=0 spectra; later v01 out
  float* row1 = hH + (size_t)(F_DIM + f) * NFFT;  // o=1 spectra

  const u16* u0 = up + (size_t)(0 * C_IN + f) * L_SEQ;
  const u16* u1 = up + (size_t)(1 * C_IN + f) * L_SEQ;
  const float vw0 = sw[f], vw1 = sw[C_IN + f], vw2 = sw[2 * C_IN + f];
  const float vb = sb[f];

  // ===== o = 0 =====
  for (int g = tid; g < 1024; g += NT) {
    float xr[2][4], xi[2][4];
    #pragma unroll
    for (int k = 0; k < 2; ++k)
      #pragma unroll
      for (int m = 0; m < 4; ++m) {
        const int t = g + (m << 10) + (k << 12);
        xr[k][m] = conv3b(u0, t, vw0, vw1, vw2, vb);
        xi[k][m] = conv3b(u1, t, vw0, vw1, vw2, vb);
      }
    s1_zero_hi(zr, zi, g, xr, xi);
  }
  __syncthreads();
  fwd_pairs<8>(zr, zi, tid);
  fused_final_spec_head(zr, zi, (const __hip_bfloat162*)rowf, tid);
  inv_mid_pairs(zr, zi, tid);

  const int c0g = F_DIM + f;
  inv_last_gate<false>(zr, zi,
      up + (size_t)(0 * C_IN + c0g) * L_SEQ,
      up + (size_t)(1 * C_IN + c0g) * L_SEQ,
      sw[c0g], sw[C_IN + c0g], sw[2 * C_IN + c0g], sb[c0g], nullptr, tid);

  // ===== o = 1 ===== (input = gated o=0 result, t<8192 in LDS)
  for (int g = tid; g < 1024; g += NT) {
    float xr[2][4], xi[2][4];
    #pragma unroll
    for (int k = 0; k < 2; ++k)
      #pragma unroll
      for (int m = 0; m < 4; ++m) {
        const int idx = PAD(g + (m << 10) + (k << 12));
        xr[k][m] = zr[idx]; xi[k][m] = zi[idx];
      }
    s1_zero_hi(zr, zi, g, xr, xi);
  }
  __syncthreads();
  fwd_pairs<8>(zr, zi, tid);
  fused_final_spec_head(zr, zi, (const __hip_bfloat162*)row1, tid);
  inv_mid_pairs(zr, zi, tid);

  const int c1g = 2 * F_DIM + f;
  inv_last_gate<true>(zr, zi,
      up + (size_t)(0 * C_IN + c1g) * L_SEQ,
      up + (size_t)(1 * C_IN + c1g) * L_SEQ,
      sw[c1g], sw[C_IN + c1g], sw[2 * C_IN + c1g], sb[c1g], (u16*)rowf, tid);
}

// ===========================================================================
extern "C" void kernel_launch(void* const* d_in, const int* in_sizes, int n_in,
                              void* d_out, int out_size, void* d_ws, size_t ws_size,
                              hipStream_t stream)
{
  (void)in_sizes; (void)n_in; (void)out_size; (void)ws_size;
  const float* u     = (const float*)d_in[0];
  const float* fw1   = (const float*)d_in[1];
  const float* fb1   = (const float*)d_in[2];
  const float* fw2   = (const float*)d_in[3];
  const float* fb2   = (const float*)d_in[4];
  const float* decay = (const float*)d_in[5];
  const float* bias  = (const float*)d_in[6];
  const float* ipw   = (const float*)d_in[7];
  const float* ipb   = (const float*)d_in[8];
  const float* sw    = (const float*)d_in[9];
  const float* sb    = (const float*)d_in[10];
  const float* ow    = (const float*)d_in[11];
  const float* ob    = (const float*)d_in[12];
  float* out = (float*)d_out;

  char* ws = (char*)d_ws;
  u16*   up_t  = (u16*)(ws);                                // 75,497,472 B
  float* hH    = (float*)(ws + 75497472);                   // 100,663,296 B
  u16*   u_bf  = (u16*)(ws + 176160768);                    // 25,165,824 B
  u16*   ipw_t = (u16*)(ws + 201326592);                    // 3,538,944 B
  u16*   ow_t  = (u16*)(ws + 204865536);                    // 1,179,648 B
  // filter-path scratch in the up_t region (dead until gemm1 runs later):
  u16*   hidb  = (u16*)(ws);                                // 2,097,152 B
  u16*   w2t   = (u16*)(ws + 2097152);                      //   196,608 B

  cast_bf16_kernel<<<dim3(12288), 256, 0, stream>>>(u, u_bf, (2 * L_SEQ * D_DIM) / 4);
  transpose_cast_kernel<<<dim3(C_IN / 32, D_DIM / 32), 256, 0, stream>>>(ipw, ipw_t, D_DIM, C_IN);
  transpose_cast_kernel<<<dim3(D_DIM / 32, F_DIM / 32), 256, 0, stream>>>(ow, ow_t, F_DIM, D_DIM);

  // filter path: hid (bf16) -> w2^T (bf16) -> MFMA h-GEMM (+decay epilogue)
  // -> packed FFT (one per channel, both orders)
  hid_gen_kernel<<<dim3(NFFT / 16), 256, 0, stream>>>(fw1, fb1, hidb);
  transpose_cast_kernel<<<dim3(1536 / 32, 64 / 32), 256, 0, stream>>>(fw2, w2t, 64, 1536);
  mfma_gemm_kernel<1536, 64, 2, 0, 0, 1><<<dim3(1536 / 128, NFFT / 128), 256, 0, stream>>>(
      hidb, w2t, fb2, hH, decay);
  filter_fft_kernel<<<dim3(F_DIM), NT, 0, stream>>>(hH, bias);

  mfma_gemm_kernel<C_IN, D_DIM, 0, 0, 0, 1><<<dim3(C_IN / 128, 128), 256, 0, stream>>>(
      u_bf, ipw_t, ipb, up_t, nullptr);
  fftconv_kernel<<<dim3(F_DIM), NT, 0, stream>>>(up_t, hH, sw, sb);
  // gemm2 reads v01 rows (u16 [f][m], stride 2*NFFT) with fused transpose
  mfma_gemm_kernel<D_DIM, F_DIM, 1, 1, 2 * NFFT, 1><<<dim3(D_DIM / 128, 128), 256, 0, stream>>>(
      (const u16*)hH, ow_t, ob, out, nullptr);
}